// Round 9
// baseline (761.874 us; speedup 1.0000x reference)
//
#include <hip/hip_runtime.h>

#define NEG 0.01f
#define NBUCK_MAX 1024  // buckets of 64 nodes; 50000/64 -> 782 used
#define CHUNK 4096      // edges per partition block

typedef unsigned int uint;
typedef unsigned short ush;
typedef __attribute__((ext_vector_type(8))) short bf8v;   // 8 bf16 = 4 VGPRs
typedef __attribute__((ext_vector_type(4))) float f4v;    // MFMA accumulator

__device__ __forceinline__ float bf2f(ush u) { return __uint_as_float(((uint)u) << 16); }
__device__ __forceinline__ ush f2bf(float f) {
  uint u = __float_as_uint(f);
  u += 0x7FFFu + ((u >> 16) & 1u);   // RNE
  return (ush)(u >> 16);
}

// edge record: (bucket<<22) | (src<<6) | dst_local   (src < 2^16, bucket < 1024)

// ---------------- P0: bucket histogram ----------------

__global__ __launch_bounds__(256) void bucket_count(const int* __restrict__ dst,
                                                    int* __restrict__ bcnt, int E) {
  __shared__ int h[NBUCK_MAX];
  int t = threadIdx.x;
  for (int b = t; b < NBUCK_MAX; b += 256) h[b] = 0;
  __syncthreads();
  int base = blockIdx.x * CHUNK;
#pragma unroll
  for (int c = 0; c < CHUNK / 256; ++c) {
    int e = base + c * 256 + t;
    if (e < E) atomicAdd(&h[dst[e] >> 6], 1);
  }
  __syncthreads();
  for (int b = t; b < NBUCK_MAX; b += 256)
    if (h[b]) atomicAdd(&bcnt[b], h[b]);
}

// ---------------- P1: scan 1024 bucket counts (1 block, 4/thread) ----------------

__global__ __launch_bounds__(256) void bucket_scan(const int* __restrict__ bcnt,
                                                   int* __restrict__ bbase,
                                                   int* __restrict__ bnext, int E) {
  __shared__ int sc[256];
  int t = threadIdx.x;
  int v0 = bcnt[4 * t], v1 = bcnt[4 * t + 1], v2 = bcnt[4 * t + 2], v3 = bcnt[4 * t + 3];
  int p = v0 + v1 + v2 + v3;
  sc[t] = p;
  __syncthreads();
  for (int off = 1; off < 256; off <<= 1) {
    int u = (t >= off) ? sc[t - off] : 0;
    __syncthreads();
    sc[t] += u;
    __syncthreads();
  }
  int run = sc[t] - p;
  bbase[4 * t] = run;     bnext[4 * t] = run;     run += v0;
  bbase[4 * t + 1] = run; bnext[4 * t + 1] = run; run += v1;
  bbase[4 * t + 2] = run; bnext[4 * t + 2] = run; run += v2;
  bbase[4 * t + 3] = run; bnext[4 * t + 3] = run;
  if (t == 255) bbase[1024] = E;
}

// ---------------- P2: partition edges into bucket-grouped packed tmp ----------------

__global__ __launch_bounds__(256) void partition_kernel(const int* __restrict__ src,
                                                        const int* __restrict__ dst,
                                                        int* __restrict__ bnext,
                                                        uint* __restrict__ tmp, int E) {
  __shared__ int hcnt[NBUCK_MAX];
  __shared__ int hbase[NBUCK_MAX];
  __shared__ int gbase[NBUCK_MAX];
  __shared__ int sc[256];
  __shared__ uint lrec[CHUNK];
  int t = threadIdx.x;
  for (int b = t; b < NBUCK_MAX; b += 256) hcnt[b] = 0;
  __syncthreads();
  int base = blockIdx.x * CHUNK;
  uint rec[CHUNK / 256];
  int slot[CHUNK / 256];
#pragma unroll
  for (int c = 0; c < CHUNK / 256; ++c) {
    int e = base + c * 256 + t;
    slot[c] = -1;
    if (e < E) {
      uint s = (uint)src[e], d = (uint)dst[e];
      uint b = d >> 6;
      rec[c] = (b << 22) | (s << 6) | (d & 63u);
      slot[c] = atomicAdd(&hcnt[b], 1);
    }
  }
  __syncthreads();
  // exclusive scan of hcnt[1024], 4 per thread
  int v0 = hcnt[4 * t], v1 = hcnt[4 * t + 1], v2 = hcnt[4 * t + 2], v3 = hcnt[4 * t + 3];
  int p = v0 + v1 + v2 + v3;
  sc[t] = p;
  __syncthreads();
  for (int off = 1; off < 256; off <<= 1) {
    int u = (t >= off) ? sc[t - off] : 0;
    __syncthreads();
    sc[t] += u;
    __syncthreads();
  }
  int run = sc[t] - p;
  hbase[4 * t] = run;     run += v0;
  hbase[4 * t + 1] = run; run += v1;
  hbase[4 * t + 2] = run; run += v2;
  hbase[4 * t + 3] = run;
  __syncthreads();
  // scatter into LDS, bucket-sorted
#pragma unroll
  for (int c = 0; c < CHUNK / 256; ++c) {
    if (slot[c] >= 0) lrec[hbase[rec[c] >> 22] + slot[c]] = rec[c];
  }
  // reserve contiguous global regions per bucket
  for (int b = t; b < NBUCK_MAX; b += 256)
    if (hcnt[b]) gbase[b] = atomicAdd(&bnext[b], hcnt[b]);
  __syncthreads();
  // linear (coalesced) write-out
  int m = min(CHUNK, E - base);
  for (int idx = t; idx < m; idx += 256) {
    uint r = lrec[idx];
    uint b = r >> 22;
    tmp[gbase[b] + (idx - hbase[b])] = r;
  }
}

// ---------------- P3: per-bucket dinv + xs = bf16(dinv ⊙ x) ----------------

__global__ __launch_bounds__(256) void dinv_xscale(const uint* __restrict__ tmp,
                                                   const int* __restrict__ bbase,
                                                   const float* __restrict__ x,
                                                   float* __restrict__ dinv,
                                                   ush* __restrict__ xs, int n) {
  __shared__ int lcnt[64];
  __shared__ float ldi[64];
  int b = blockIdx.x, t = threadIdx.x;
  int node0 = b << 6;
  if (t < 64) lcnt[t] = 0;
  __syncthreads();
  int rp0 = bbase[b], rp1 = bbase[b + 1];
  for (int idx = rp0 + t; idx < rp1; idx += 256)
    atomicAdd(&lcnt[tmp[idx] & 63u], 1);
  __syncthreads();
  if (t < 64) {
    int node = node0 + t;
    float di = rsqrtf((float)lcnt[t] + 1.0f);  // +1 self-loop
    ldi[t] = di;
    if (node < n) dinv[node] = di;
  }
  __syncthreads();
  for (int idx = t; idx < 64 * 16; idx += 256) {
    int nl = idx >> 4, q = idx & 15;
    int node = node0 + nl;
    if (node < n) {
      float di = ldi[nl];
      float4 v = *(const float4*)&x[(size_t)node * 64 + q * 4];
      ushort4 o;
      o.x = f2bf(v.x * di);
      o.y = f2bf(v.y * di);
      o.z = f2bf(v.z * di);
      o.w = f2bf(v.w * di);
      *(ushort4*)&xs[(size_t)node * 64 + q * 4] = o;
    }
  }
}

// ---------------- Aggregation: edge-parallel per bucket, LDS f32 accumulate ----------------
// acc[dl][f] = row_dl's running sum; init with self term; ds_add per edge.

// axs[i,:] = bf16( dinv[i] * ( sum_{s in N(i)} xs[s,:] + xs[i,:] ) )
__global__ __launch_bounds__(256) void agg1_bucket(const ush* __restrict__ xs,
                                                   const float* __restrict__ dinv,
                                                   const uint* __restrict__ tmp,
                                                   const int* __restrict__ bbase,
                                                   ush* __restrict__ axs, int n) {
  __shared__ float acc[64][68];   // padded: group offsets spread banks
  int b = blockIdx.x, t = threadIdx.x;
  int node0 = b << 6;
  int fl = t & 15, grp = t >> 4;   // 16 groups x 16 lanes
  for (int idx = t; idx < 64 * 16; idx += 256) {
    int nl = idx >> 4, q = idx & 15;
    int node = node0 + nl;
    if (node < n) {
      ushort4 u = *(const ushort4*)&xs[(size_t)node * 64 + q * 4];
      acc[nl][q * 4 + 0] = bf2f(u.x);
      acc[nl][q * 4 + 1] = bf2f(u.y);
      acc[nl][q * 4 + 2] = bf2f(u.z);
      acc[nl][q * 4 + 3] = bf2f(u.w);
    } else {
      acc[nl][q * 4 + 0] = 0.f; acc[nl][q * 4 + 1] = 0.f;
      acc[nl][q * 4 + 2] = 0.f; acc[nl][q * 4 + 3] = 0.f;
    }
  }
  __syncthreads();
  int rp0 = bbase[b], rp1 = bbase[b + 1];
  int e = rp0 + grp;
  for (; e + 16 < rp1; e += 32) {   // 2 edges in flight per group
    uint r0 = tmp[e], r1 = tmp[e + 16];
    int s0 = (int)((r0 >> 6) & 0xFFFFu), d0 = (int)(r0 & 63u);
    int s1 = (int)((r1 >> 6) & 0xFFFFu), d1 = (int)(r1 & 63u);
    ushort4 u0 = *(const ushort4*)&xs[(size_t)s0 * 64 + fl * 4];
    ushort4 u1 = *(const ushort4*)&xs[(size_t)s1 * 64 + fl * 4];
    atomicAdd(&acc[d0][fl * 4 + 0], bf2f(u0.x));
    atomicAdd(&acc[d0][fl * 4 + 1], bf2f(u0.y));
    atomicAdd(&acc[d0][fl * 4 + 2], bf2f(u0.z));
    atomicAdd(&acc[d0][fl * 4 + 3], bf2f(u0.w));
    atomicAdd(&acc[d1][fl * 4 + 0], bf2f(u1.x));
    atomicAdd(&acc[d1][fl * 4 + 1], bf2f(u1.y));
    atomicAdd(&acc[d1][fl * 4 + 2], bf2f(u1.z));
    atomicAdd(&acc[d1][fl * 4 + 3], bf2f(u1.w));
  }
  if (e < rp1) {
    uint r0 = tmp[e];
    int s0 = (int)((r0 >> 6) & 0xFFFFu), d0 = (int)(r0 & 63u);
    ushort4 u0 = *(const ushort4*)&xs[(size_t)s0 * 64 + fl * 4];
    atomicAdd(&acc[d0][fl * 4 + 0], bf2f(u0.x));
    atomicAdd(&acc[d0][fl * 4 + 1], bf2f(u0.y));
    atomicAdd(&acc[d0][fl * 4 + 2], bf2f(u0.z));
    atomicAdd(&acc[d0][fl * 4 + 3], bf2f(u0.w));
  }
  __syncthreads();
  for (int idx = t; idx < 64 * 16; idx += 256) {
    int nl = idx >> 4, q = idx & 15;
    int node = node0 + nl;
    if (node < n) {
      float di = dinv[node];
      ushort4 o;
      o.x = f2bf(di * acc[nl][q * 4 + 0]);
      o.y = f2bf(di * acc[nl][q * 4 + 1]);
      o.z = f2bf(di * acc[nl][q * 4 + 2]);
      o.w = f2bf(di * acc[nl][q * 4 + 3]);
      *(ushort4*)&axs[(size_t)node * 64 + q * 4] = o;
    }
  }
}

// out[i,:] = x[i,:] + b2 + dinv[i] * ( sum h2s[s,:] + h2s[i,:] )
__global__ __launch_bounds__(256) void agg2_bucket(const ush* __restrict__ h2s,
                                                   const float* __restrict__ dinv,
                                                   const uint* __restrict__ tmp,
                                                   const int* __restrict__ bbase,
                                                   const float* __restrict__ bias,
                                                   const float* __restrict__ x,
                                                   float* __restrict__ out, int n) {
  __shared__ float acc[64][68];
  int b = blockIdx.x, t = threadIdx.x;
  int node0 = b << 6;
  int fl = t & 15, grp = t >> 4;
  for (int idx = t; idx < 64 * 16; idx += 256) {
    int nl = idx >> 4, q = idx & 15;
    int node = node0 + nl;
    if (node < n) {
      ushort4 u = *(const ushort4*)&h2s[(size_t)node * 64 + q * 4];
      acc[nl][q * 4 + 0] = bf2f(u.x);
      acc[nl][q * 4 + 1] = bf2f(u.y);
      acc[nl][q * 4 + 2] = bf2f(u.z);
      acc[nl][q * 4 + 3] = bf2f(u.w);
    } else {
      acc[nl][q * 4 + 0] = 0.f; acc[nl][q * 4 + 1] = 0.f;
      acc[nl][q * 4 + 2] = 0.f; acc[nl][q * 4 + 3] = 0.f;
    }
  }
  __syncthreads();
  int rp0 = bbase[b], rp1 = bbase[b + 1];
  int e = rp0 + grp;
  for (; e + 16 < rp1; e += 32) {
    uint r0 = tmp[e], r1 = tmp[e + 16];
    int s0 = (int)((r0 >> 6) & 0xFFFFu), d0 = (int)(r0 & 63u);
    int s1 = (int)((r1 >> 6) & 0xFFFFu), d1 = (int)(r1 & 63u);
    ushort4 u0 = *(const ushort4*)&h2s[(size_t)s0 * 64 + fl * 4];
    ushort4 u1 = *(const ushort4*)&h2s[(size_t)s1 * 64 + fl * 4];
    atomicAdd(&acc[d0][fl * 4 + 0], bf2f(u0.x));
    atomicAdd(&acc[d0][fl * 4 + 1], bf2f(u0.y));
    atomicAdd(&acc[d0][fl * 4 + 2], bf2f(u0.z));
    atomicAdd(&acc[d0][fl * 4 + 3], bf2f(u0.w));
    atomicAdd(&acc[d1][fl * 4 + 0], bf2f(u1.x));
    atomicAdd(&acc[d1][fl * 4 + 1], bf2f(u1.y));
    atomicAdd(&acc[d1][fl * 4 + 2], bf2f(u1.z));
    atomicAdd(&acc[d1][fl * 4 + 3], bf2f(u1.w));
  }
  if (e < rp1) {
    uint r0 = tmp[e];
    int s0 = (int)((r0 >> 6) & 0xFFFFu), d0 = (int)(r0 & 63u);
    ushort4 u0 = *(const ushort4*)&h2s[(size_t)s0 * 64 + fl * 4];
    atomicAdd(&acc[d0][fl * 4 + 0], bf2f(u0.x));
    atomicAdd(&acc[d0][fl * 4 + 1], bf2f(u0.y));
    atomicAdd(&acc[d0][fl * 4 + 2], bf2f(u0.z));
    atomicAdd(&acc[d0][fl * 4 + 3], bf2f(u0.w));
  }
  __syncthreads();
  for (int idx = t; idx < 64 * 16; idx += 256) {
    int nl = idx >> 4, q = idx & 15;
    int node = node0 + nl;
    if (node < n) {
      float di = dinv[node];
      float4 xr = *(const float4*)&x[(size_t)node * 64 + q * 4];
      float4 bb = *(const float4*)&bias[q * 4];
      float4 o;
      o.x = xr.x + bb.x + di * acc[nl][q * 4 + 0];
      o.y = xr.y + bb.y + di * acc[nl][q * 4 + 1];
      o.z = xr.z + bb.z + di * acc[nl][q * 4 + 2];
      o.w = xr.w + bb.w + di * acc[nl][q * 4 + 3];
      *(float4*)&out[(size_t)node * 64 + q * 4] = o;
    }
  }
}

// ---------------- GEMMs via MFMA; W staged from immutable d_in into LDS ----------------

#define P1 88    // w1 LDS row length in bf16
#define P2 136   // w2 LDS row length in bf16

// y1[n,128] = bf16( leaky(axs[n,64] @ W1 + b1) )
__global__ __launch_bounds__(256) void gemm1_mfma(const ush* __restrict__ axs,
                                                  const float* __restrict__ W,
                                                  const float* __restrict__ b,
                                                  ush* __restrict__ y1, int n) {
  __shared__ ush wl[128 * P1];   // 22.5 KB
  int t = threadIdx.x;
  for (int idx = t; idx < 128 * 64; idx += 256) {
    int j = idx >> 6, k = idx & 63;
    wl[j * P1 + k] = f2bf(W[k * 128 + j]);
  }
  __syncthreads();
  int lane = t & 63;
  int m = lane & 15, kq = lane >> 4;
  int ntiles = (n + 15) >> 4;
  for (int wid = blockIdx.x * 4 + (t >> 6); wid < ntiles; wid += gridDim.x * 4) {
    int node0 = wid << 4;
    int arow = min(node0 + m, n - 1);
    bf8v a0 = *(const bf8v*)&axs[(size_t)arow * 64 + kq * 8];
    bf8v a1 = *(const bf8v*)&axs[(size_t)arow * 64 + 32 + kq * 8];
#pragma unroll
    for (int j0 = 0; j0 < 128; j0 += 16) {
      const ush* wt = &wl[(j0 + m) * P1 + kq * 8];
      bf8v b0 = *(const bf8v*)wt;
      bf8v b1 = *(const bf8v*)(wt + 32);
      f4v acc = {0.f, 0.f, 0.f, 0.f};
      acc = __builtin_amdgcn_mfma_f32_16x16x32_bf16(a0, b0, acc, 0, 0, 0);
      acc = __builtin_amdgcn_mfma_f32_16x16x32_bf16(a1, b1, acc, 0, 0, 0);
      float bias = b[j0 + m];
#pragma unroll
      for (int r = 0; r < 4; ++r) {
        int orow = node0 + kq * 4 + r;
        if (orow < n) {
          float s = acc[r] + bias;
          s = (s >= 0.f) ? s : NEG * s;
          y1[(size_t)orow * 128 + j0 + m] = f2bf(s);
        }
      }
    }
  }
}

// h2s[n,64] = bf16( dinv ⊙ (y1[n,128] @ W2) )
__global__ __launch_bounds__(256) void gemm2_mfma(const ush* __restrict__ y1,
                                                  const float* __restrict__ W,
                                                  const float* __restrict__ dinv,
                                                  ush* __restrict__ h2s, int n) {
  __shared__ ush wl[64 * P2];   // 17.4 KB
  int t = threadIdx.x;
  for (int idx = t; idx < 64 * 128; idx += 256) {
    int j = idx >> 7, k = idx & 127;
    wl[j * P2 + k] = f2bf(W[k * 64 + j]);
  }
  __syncthreads();
  int lane = t & 63;
  int m = lane & 15, kq = lane >> 4;
  int ntiles = (n + 15) >> 4;
  for (int wid = blockIdx.x * 4 + (t >> 6); wid < ntiles; wid += gridDim.x * 4) {
    int node0 = wid << 4;
    int arow = min(node0 + m, n - 1);
    const ush* ap = &y1[(size_t)arow * 128 + kq * 8];
    bf8v a0 = *(const bf8v*)(ap);
    bf8v a1 = *(const bf8v*)(ap + 32);
    bf8v a2 = *(const bf8v*)(ap + 64);
    bf8v a3 = *(const bf8v*)(ap + 96);
    float dv[4];
#pragma unroll
    for (int r = 0; r < 4; ++r) dv[r] = dinv[min(node0 + kq * 4 + r, n - 1)];
#pragma unroll
    for (int j0 = 0; j0 < 64; j0 += 16) {
      const ush* wt = &wl[(j0 + m) * P2 + kq * 8];
      f4v acc = {0.f, 0.f, 0.f, 0.f};
      acc = __builtin_amdgcn_mfma_f32_16x16x32_bf16(a0, *(const bf8v*)(wt), acc, 0, 0, 0);
      acc = __builtin_amdgcn_mfma_f32_16x16x32_bf16(a1, *(const bf8v*)(wt + 32), acc, 0, 0, 0);
      acc = __builtin_amdgcn_mfma_f32_16x16x32_bf16(a2, *(const bf8v*)(wt + 64), acc, 0, 0, 0);
      acc = __builtin_amdgcn_mfma_f32_16x16x32_bf16(a3, *(const bf8v*)(wt + 96), acc, 0, 0, 0);
#pragma unroll
      for (int r = 0; r < 4; ++r) {
        int orow = node0 + kq * 4 + r;
        if (orow < n) h2s[(size_t)orow * 64 + j0 + m] = f2bf(acc[r] * dv[r]);
      }
    }
  }
}

// ---------------- launch ----------------

extern "C" void kernel_launch(void* const* d_in, const int* in_sizes, int n_in,
                              void* d_out, int out_size, void* d_ws, size_t ws_size,
                              hipStream_t stream) {
  const int n = in_sizes[0] / 64;   // 50000
  const int E = in_sizes[5] / 2;    // 800000

  const float* x  = (const float*)d_in[0];
  const float* W1 = (const float*)d_in[1];
  const float* b1 = (const float*)d_in[2];
  const float* W2 = (const float*)d_in[3];
  const float* b2 = (const float*)d_in[4];
  const int* edge = (const int*)d_in[5];
  const int* esrc = edge;
  const int* edst = edge + E;

  char* ws = (char*)d_ws;
  size_t o = 0;
  auto take = [&](size_t bytes) -> void* {
    void* p = ws + o;
    o += (bytes + 255) & ~(size_t)255;
    return p;
  };
  const int NBUCK = (n + 63) >> 6;   // 782
  int*   bcnt    = (int*)take(NBUCK_MAX * 4);
  int*   bbase   = (int*)take((NBUCK_MAX + 1) * 4);
  int*   bnext   = (int*)take(NBUCK_MAX * 4);
  float* dinv    = (float*)take((size_t)n * 4);
  uint*  tmp     = (uint*)take((size_t)E * 4);
  ush*   xs      = (ush*)take((size_t)n * 64 * 2);
  ush*   axs     = (ush*)take((size_t)n * 64 * 2);
  ush*   y1      = (ush*)take((size_t)n * 128 * 2);
  ush*   h2s     = xs;  // xs dead after agg1; reuse

  hipMemsetAsync(bcnt, 0, NBUCK_MAX * 4, stream);

  int pb = (E + CHUNK - 1) / CHUNK;  // 196
  bucket_count<<<pb, 256, 0, stream>>>(edst, bcnt, E);
  bucket_scan<<<1, 256, 0, stream>>>(bcnt, bbase, bnext, E);
  partition_kernel<<<pb, 256, 0, stream>>>(esrc, edst, bnext, tmp, E);
  dinv_xscale<<<NBUCK, 256, 0, stream>>>(tmp, bbase, x, dinv, xs, n);

  agg1_bucket<<<NBUCK, 256, 0, stream>>>(xs, dinv, tmp, bbase, axs, n);
  gemm1_mfma<<<512, 256, 0, stream>>>(axs, W1, b1, y1, n);
  gemm2_mfma<<<512, 256, 0, stream>>>(y1, W2, dinv, h2s, n);
  agg2_bucket<<<NBUCK, 256, 0, stream>>>(h2s, dinv, tmp, bbase, b2, x,
                                         (float*)d_out, n);
}

// Round 11
// 123.762 us; speedup vs baseline: 6.1560x; 6.1560x over previous
//
#include <hip/hip_runtime.h>

#define NEG 0.01f
#define NBUCK_MAX 512   // buckets of 128 nodes; 50000/128 -> 391 used
#define CHUNK 4096      // edges per partition block
#define CAP 4096        // LDS edge capacity in finalize (avg bucket ~2046)

typedef unsigned int uint;
typedef unsigned short ush;
typedef __attribute__((ext_vector_type(8))) short bf8v;            // 8 bf16 = 4 VGPRs
typedef __attribute__((ext_vector_type(8))) unsigned short us8v;   // 8 bf16 raw
typedef __attribute__((ext_vector_type(4))) float f4v;             // MFMA accumulator

__device__ __forceinline__ float bf2f(ush u) { return __uint_as_float(((uint)u) << 16); }
__device__ __forceinline__ ush f2bf(float f) {
  uint u = __float_as_uint(f);
  u += 0x7FFFu + ((u >> 16) & 1u);   // RNE
  return (ush)(u >> 16);
}

// edge record: (bucket<<23) | (src<<7) | dst_local   (src < 2^16, bucket < 512)

// ---------------- P0: bucket histogram (LDS-staged) ----------------

__global__ __launch_bounds__(256) void bucket_count(const int* __restrict__ dst,
                                                    int* __restrict__ bcnt, int E) {
  __shared__ int h[NBUCK_MAX];
  int t = threadIdx.x;
  for (int b = t; b < NBUCK_MAX; b += 256) h[b] = 0;
  __syncthreads();
  int base = blockIdx.x * CHUNK;
#pragma unroll
  for (int c = 0; c < CHUNK / 256; ++c) {
    int e = base + c * 256 + t;
    if (e < E) atomicAdd(&h[dst[e] >> 7], 1);
  }
  __syncthreads();
  for (int b = t; b < NBUCK_MAX; b += 256)
    if (h[b]) atomicAdd(&bcnt[b], h[b]);
}

// ---------------- P1: scan 512 bucket counts (1 block) ----------------

__global__ __launch_bounds__(256) void bucket_scan(const int* __restrict__ bcnt,
                                                   int* __restrict__ bbase,
                                                   int* __restrict__ bnext, int E) {
  __shared__ int sc[256];
  int t = threadIdx.x;
  int s0 = bcnt[2 * t], s1 = bcnt[2 * t + 1];
  int p = s0 + s1;
  sc[t] = p;
  __syncthreads();
  for (int off = 1; off < 256; off <<= 1) {
    int v = (t >= off) ? sc[t - off] : 0;
    __syncthreads();
    sc[t] += v;
    __syncthreads();
  }
  int ex = sc[t] - p;
  bbase[2 * t] = ex;
  bbase[2 * t + 1] = ex + s0;
  bnext[2 * t] = ex;
  bnext[2 * t + 1] = ex + s0;
  if (t == 255) bbase[512] = E;
}

// ---------------- P2: partition edges into bucket-grouped packed tmp ----------------

__global__ __launch_bounds__(256) void partition_kernel(const int* __restrict__ src,
                                                        const int* __restrict__ dst,
                                                        int* __restrict__ bnext,
                                                        uint* __restrict__ tmp, int E) {
  __shared__ int hcnt[NBUCK_MAX];
  __shared__ int hbase[NBUCK_MAX];
  __shared__ int gbase[NBUCK_MAX];
  __shared__ int sc[256];
  __shared__ uint lrec[CHUNK];
  int t = threadIdx.x;
  for (int b = t; b < NBUCK_MAX; b += 256) hcnt[b] = 0;
  __syncthreads();
  int base = blockIdx.x * CHUNK;
  uint rec[CHUNK / 256];
  int slot[CHUNK / 256];
#pragma unroll
  for (int c = 0; c < CHUNK / 256; ++c) {
    int e = base + c * 256 + t;
    slot[c] = -1;
    if (e < E) {
      uint s = (uint)src[e], d = (uint)dst[e];
      uint b = d >> 7;
      rec[c] = (b << 23) | (s << 7) | (d & 127u);
      slot[c] = atomicAdd(&hcnt[b], 1);
    }
  }
  __syncthreads();
  int s0 = hcnt[2 * t], s1 = hcnt[2 * t + 1];
  int p = s0 + s1;
  sc[t] = p;
  __syncthreads();
  for (int off = 1; off < 256; off <<= 1) {
    int v = (t >= off) ? sc[t - off] : 0;
    __syncthreads();
    sc[t] += v;
    __syncthreads();
  }
  int ex = sc[t] - p;
  hbase[2 * t] = ex;
  hbase[2 * t + 1] = ex + s0;
  __syncthreads();
#pragma unroll
  for (int c = 0; c < CHUNK / 256; ++c) {
    if (slot[c] >= 0) lrec[hbase[rec[c] >> 23] + slot[c]] = rec[c];
  }
  for (int b = t; b < NBUCK_MAX; b += 256)
    if (hcnt[b]) gbase[b] = atomicAdd(&bnext[b], hcnt[b]);
  __syncthreads();
  int m = min(CHUNK, E - base);
  for (int idx = t; idx < m; idx += 256) {
    uint r = lrec[idx];
    uint b = r >> 23;
    tmp[gbase[b] + (idx - hbase[b])] = r;
  }
}

// ---------------- P3: per-bucket CSR finalize: row_ptr, dinv, sorted col, xs ----------------

__global__ __launch_bounds__(256) void csr_finalize(const uint* __restrict__ tmp,
                                                    const int* __restrict__ bbase,
                                                    const float* __restrict__ x,
                                                    int* __restrict__ row_ptr,
                                                    float* __restrict__ dinv,
                                                    int* __restrict__ col,
                                                    ush* __restrict__ xs, int n, int E) {
  __shared__ int lcnt[128];
  __shared__ int lnxt[128];
  __shared__ int lsc[128];
  __shared__ float ldi[128];
  __shared__ uint lcol[CAP];
  int b = blockIdx.x;
  int t = threadIdx.x;
  int node0 = b << 7;
  int rp0 = bbase[b], rp1 = bbase[b + 1];
  int m = rp1 - rp0;
  if (t < 128) lcnt[t] = 0;
  __syncthreads();
  for (int idx = t; idx < m; idx += 256)
    atomicAdd(&lcnt[tmp[rp0 + idx] & 127u], 1);
  __syncthreads();
  if (t < 128) lsc[t] = lcnt[t];
  __syncthreads();
  for (int off = 1; off < 128; off <<= 1) {
    int v = 0;
    if (t < 128 && t >= off) v = lsc[t - off];
    __syncthreads();
    if (t < 128) lsc[t] += v;
    __syncthreads();
  }
  if (t < 128) {
    int node = node0 + t;
    int ex = lsc[t] - lcnt[t];
    float di = rsqrtf((float)lcnt[t] + 1.0f);  // +1 self-loop
    ldi[t] = di;
    if (node < n) {
      row_ptr[node] = rp0 + ex;
      dinv[node] = di;
    }
    lnxt[t] = ex;
  }
  if (b == (int)gridDim.x - 1 && t == 0) row_ptr[n] = E;
  __syncthreads();
  if (m <= CAP) {
    for (int idx = t; idx < m; idx += 256) {
      uint r = tmp[rp0 + idx];
      int p = atomicAdd(&lnxt[(int)(r & 127u)], 1);
      lcol[p] = (r >> 7) & 0xFFFFu;
    }
    __syncthreads();
    for (int idx = t; idx < m; idx += 256) col[rp0 + idx] = (int)lcol[idx];
  } else {  // statistically unreachable
    for (int idx = t; idx < m; idx += 256) {
      uint r = tmp[rp0 + idx];
      int p = atomicAdd(&lnxt[(int)(r & 127u)], 1);
      col[rp0 + p] = (int)((r >> 7) & 0xFFFFu);
    }
  }
  // fused xs = bf16(dinv ⊙ x) for this bucket's nodes
  for (int idx = t; idx < 128 * 16; idx += 256) {
    int nl = idx >> 4, q = idx & 15;
    int node = node0 + nl;
    if (node < n) {
      float di = ldi[nl];
      float4 v = *(const float4*)&x[(size_t)node * 64 + q * 4];
      ushort4 o;
      o.x = f2bf(v.x * di);
      o.y = f2bf(v.y * di);
      o.z = f2bf(v.z * di);
      o.w = f2bf(v.w * di);
      *(ushort4*)&xs[(size_t)node * 64 + q * 4] = o;
    }
  }
}

// ---------------- Aggregation: 1 wave/node, 8 lanes x ushort8 (16B) per row ----------------
// 8 edges per VMEM instr, 16 in flight with 2-deep unroll.

// axs[i,:] = bf16( dinv[i] * ( sum_{s in N(i)} xs[s,:] + xs[i,:] ) )
__global__ __launch_bounds__(256) void aggx_kernel(const ush* __restrict__ xs,
                                                   const float* __restrict__ dinv,
                                                   const int* __restrict__ row_ptr,
                                                   const int* __restrict__ col,
                                                   ush* __restrict__ axs, int n) {
  int lane = threadIdx.x & 63;
  int g = lane >> 3, fl = lane & 7;
  int i = blockIdx.x * 4 + (threadIdx.x >> 6);
  if (i >= n) return;
  int e0 = row_ptr[i], e1 = row_ptr[i + 1];
  float a0[8] = {0.f, 0.f, 0.f, 0.f, 0.f, 0.f, 0.f, 0.f};
  float a1[8] = {0.f, 0.f, 0.f, 0.f, 0.f, 0.f, 0.f, 0.f};
  int e = e0;
  for (; e + 16 <= e1; e += 16) {
    int c0 = col[e + g], c1 = col[e + 8 + g];
    us8v u0 = *(const us8v*)&xs[(size_t)c0 * 64 + fl * 8];
    us8v u1 = *(const us8v*)&xs[(size_t)c1 * 64 + fl * 8];
#pragma unroll
    for (int q = 0; q < 8; ++q) a0[q] += bf2f(u0[q]);
#pragma unroll
    for (int q = 0; q < 8; ++q) a1[q] += bf2f(u1[q]);
  }
  for (; e < e1; e += 8) {
    int eg = e + g;
    bool valid = eg < e1;
    int c = col[valid ? eg : e];
    us8v u = *(const us8v*)&xs[(size_t)c * 64 + fl * 8];
    float msk = valid ? 1.f : 0.f;
#pragma unroll
    for (int q = 0; q < 8; ++q) a0[q] = fmaf(msk, bf2f(u[q]), a0[q]);
  }
#pragma unroll
  for (int q = 0; q < 8; ++q) a0[q] += a1[q];
#pragma unroll
  for (int q = 0; q < 8; ++q) a0[q] += __shfl_xor(a0[q], 8);
#pragma unroll
  for (int q = 0; q < 8; ++q) a0[q] += __shfl_xor(a0[q], 16);
#pragma unroll
  for (int q = 0; q < 8; ++q) a0[q] += __shfl_xor(a0[q], 32);
  if (g == 0) {
    us8v us = *(const us8v*)&xs[(size_t)i * 64 + fl * 8];
    float di = dinv[i];
    us8v o;
#pragma unroll
    for (int q = 0; q < 8; ++q) o[q] = f2bf(di * (a0[q] + bf2f(us[q])));
    *(us8v*)&axs[(size_t)i * 64 + fl * 8] = o;
  }
}

// out[i,:] = x[i,:] + b2 + dinv[i] * ( sum h2s[s,:] + h2s[i,:] )
__global__ __launch_bounds__(256) void agg2_kernel(const ush* __restrict__ h2s,
                                                   const float* __restrict__ dinv,
                                                   const int* __restrict__ row_ptr,
                                                   const int* __restrict__ col,
                                                   const float* __restrict__ bias,
                                                   const float* __restrict__ x,
                                                   float* __restrict__ out, int n) {
  int lane = threadIdx.x & 63;
  int g = lane >> 3, fl = lane & 7;
  int i = blockIdx.x * 4 + (threadIdx.x >> 6);
  if (i >= n) return;
  int e0 = row_ptr[i], e1 = row_ptr[i + 1];
  float a0[8] = {0.f, 0.f, 0.f, 0.f, 0.f, 0.f, 0.f, 0.f};
  float a1[8] = {0.f, 0.f, 0.f, 0.f, 0.f, 0.f, 0.f, 0.f};
  int e = e0;
  for (; e + 16 <= e1; e += 16) {
    int c0 = col[e + g], c1 = col[e + 8 + g];
    us8v u0 = *(const us8v*)&h2s[(size_t)c0 * 64 + fl * 8];
    us8v u1 = *(const us8v*)&h2s[(size_t)c1 * 64 + fl * 8];
#pragma unroll
    for (int q = 0; q < 8; ++q) a0[q] += bf2f(u0[q]);
#pragma unroll
    for (int q = 0; q < 8; ++q) a1[q] += bf2f(u1[q]);
  }
  for (; e < e1; e += 8) {
    int eg = e + g;
    bool valid = eg < e1;
    int c = col[valid ? eg : e];
    us8v u = *(const us8v*)&h2s[(size_t)c * 64 + fl * 8];
    float msk = valid ? 1.f : 0.f;
#pragma unroll
    for (int q = 0; q < 8; ++q) a0[q] = fmaf(msk, bf2f(u[q]), a0[q]);
  }
#pragma unroll
  for (int q = 0; q < 8; ++q) a0[q] += a1[q];
#pragma unroll
  for (int q = 0; q < 8; ++q) a0[q] += __shfl_xor(a0[q], 8);
#pragma unroll
  for (int q = 0; q < 8; ++q) a0[q] += __shfl_xor(a0[q], 16);
#pragma unroll
  for (int q = 0; q < 8; ++q) a0[q] += __shfl_xor(a0[q], 32);
  if (g == 0) {
    us8v us = *(const us8v*)&h2s[(size_t)i * 64 + fl * 8];
    float di = dinv[i];
    float4 xr0 = *(const float4*)&x[(size_t)i * 64 + fl * 8];
    float4 xr1 = *(const float4*)&x[(size_t)i * 64 + fl * 8 + 4];
    float4 bb0 = *(const float4*)&bias[fl * 8];
    float4 bb1 = *(const float4*)&bias[fl * 8 + 4];
    float4 o0, o1;
    o0.x = xr0.x + bb0.x + di * (a0[0] + bf2f(us[0]));
    o0.y = xr0.y + bb0.y + di * (a0[1] + bf2f(us[1]));
    o0.z = xr0.z + bb0.z + di * (a0[2] + bf2f(us[2]));
    o0.w = xr0.w + bb0.w + di * (a0[3] + bf2f(us[3]));
    o1.x = xr1.x + bb1.x + di * (a0[4] + bf2f(us[4]));
    o1.y = xr1.y + bb1.y + di * (a0[5] + bf2f(us[5]));
    o1.z = xr1.z + bb1.z + di * (a0[6] + bf2f(us[6]));
    o1.w = xr1.w + bb1.w + di * (a0[7] + bf2f(us[7]));
    *(float4*)&out[(size_t)i * 64 + fl * 8] = o0;
    *(float4*)&out[(size_t)i * 64 + fl * 8 + 4] = o1;
  }
}

// ---------------- GEMMs via MFMA; W staged from immutable d_in into LDS ----------------

#define P1 88    // w1 LDS row length in bf16
#define P2 136   // w2 LDS row length in bf16

// y1[n,128] = bf16( leaky(axs[n,64] @ W1 + b1) )
__global__ __launch_bounds__(256) void gemm1_mfma(const ush* __restrict__ axs,
                                                  const float* __restrict__ W,
                                                  const float* __restrict__ b,
                                                  ush* __restrict__ y1, int n) {
  __shared__ ush wl[128 * P1];   // 22.5 KB
  int t = threadIdx.x;
  for (int idx = t; idx < 128 * 64; idx += 256) {
    int j = idx >> 6, k = idx & 63;
    wl[j * P1 + k] = f2bf(W[k * 128 + j]);
  }
  __syncthreads();
  int lane = t & 63;
  int m = lane & 15, kq = lane >> 4;
  int ntiles = (n + 15) >> 4;
  for (int wid = blockIdx.x * 4 + (t >> 6); wid < ntiles; wid += gridDim.x * 4) {
    int node0 = wid << 4;
    int arow = min(node0 + m, n - 1);
    bf8v a0 = *(const bf8v*)&axs[(size_t)arow * 64 + kq * 8];
    bf8v a1 = *(const bf8v*)&axs[(size_t)arow * 64 + 32 + kq * 8];
#pragma unroll
    for (int j0 = 0; j0 < 128; j0 += 16) {
      const ush* wt = &wl[(j0 + m) * P1 + kq * 8];
      bf8v b0 = *(const bf8v*)wt;
      bf8v b1 = *(const bf8v*)(wt + 32);
      f4v acc = {0.f, 0.f, 0.f, 0.f};
      acc = __builtin_amdgcn_mfma_f32_16x16x32_bf16(a0, b0, acc, 0, 0, 0);
      acc = __builtin_amdgcn_mfma_f32_16x16x32_bf16(a1, b1, acc, 0, 0, 0);
      float bias = b[j0 + m];
#pragma unroll
      for (int r = 0; r < 4; ++r) {
        int orow = node0 + kq * 4 + r;
        if (orow < n) {
          float s = acc[r] + bias;
          s = (s >= 0.f) ? s : NEG * s;
          y1[(size_t)orow * 128 + j0 + m] = f2bf(s);
        }
      }
    }
  }
}

// h2s[n,64] = bf16( dinv ⊙ (y1[n,128] @ W2) )
__global__ __launch_bounds__(256) void gemm2_mfma(const ush* __restrict__ y1,
                                                  const float* __restrict__ W,
                                                  const float* __restrict__ dinv,
                                                  ush* __restrict__ h2s, int n) {
  __shared__ ush wl[64 * P2];   // 17.4 KB
  int t = threadIdx.x;
  for (int idx = t; idx < 64 * 128; idx += 256) {
    int j = idx >> 7, k = idx & 127;
    wl[j * P2 + k] = f2bf(W[k * 64 + j]);
  }
  __syncthreads();
  int lane = t & 63;
  int m = lane & 15, kq = lane >> 4;
  int ntiles = (n + 15) >> 4;
  for (int wid = blockIdx.x * 4 + (t >> 6); wid < ntiles; wid += gridDim.x * 4) {
    int node0 = wid << 4;
    int arow = min(node0 + m, n - 1);
    const ush* ap = &y1[(size_t)arow * 128 + kq * 8];
    bf8v a0 = *(const bf8v*)(ap);
    bf8v a1 = *(const bf8v*)(ap + 32);
    bf8v a2 = *(const bf8v*)(ap + 64);
    bf8v a3 = *(const bf8v*)(ap + 96);
    float dv[4];
#pragma unroll
    for (int r = 0; r < 4; ++r) dv[r] = dinv[min(node0 + kq * 4 + r, n - 1)];
#pragma unroll
    for (int j0 = 0; j0 < 64; j0 += 16) {
      const ush* wt = &wl[(j0 + m) * P2 + kq * 8];
      f4v acc = {0.f, 0.f, 0.f, 0.f};
      acc = __builtin_amdgcn_mfma_f32_16x16x32_bf16(a0, *(const bf8v*)(wt), acc, 0, 0, 0);
      acc = __builtin_amdgcn_mfma_f32_16x16x32_bf16(a1, *(const bf8v*)(wt + 32), acc, 0, 0, 0);
      acc = __builtin_amdgcn_mfma_f32_16x16x32_bf16(a2, *(const bf8v*)(wt + 64), acc, 0, 0, 0);
      acc = __builtin_amdgcn_mfma_f32_16x16x32_bf16(a3, *(const bf8v*)(wt + 96), acc, 0, 0, 0);
#pragma unroll
      for (int r = 0; r < 4; ++r) {
        int orow = node0 + kq * 4 + r;
        if (orow < n) h2s[(size_t)orow * 64 + j0 + m] = f2bf(acc[r] * dv[r]);
      }
    }
  }
}

// ---------------- launch ----------------

extern "C" void kernel_launch(void* const* d_in, const int* in_sizes, int n_in,
                              void* d_out, int out_size, void* d_ws, size_t ws_size,
                              hipStream_t stream) {
  const int n = in_sizes[0] / 64;   // 50000
  const int E = in_sizes[5] / 2;    // 800000

  const float* x  = (const float*)d_in[0];
  const float* W1 = (const float*)d_in[1];
  const float* b1 = (const float*)d_in[2];
  const float* W2 = (const float*)d_in[3];
  const float* b2 = (const float*)d_in[4];
  const int* edge = (const int*)d_in[5];
  const int* esrc = edge;
  const int* edst = edge + E;

  char* ws = (char*)d_ws;
  size_t o = 0;
  auto take = [&](size_t bytes) -> void* {
    void* p = ws + o;
    o += (bytes + 255) & ~(size_t)255;
    return p;
  };
  const int NBUCK = (n + 127) >> 7;  // 391
  int*   bcnt    = (int*)take(NBUCK_MAX * 4);
  int*   bbase   = (int*)take((NBUCK_MAX + 1) * 4);
  int*   bnext   = (int*)take(NBUCK_MAX * 4);
  int*   row_ptr = (int*)take((size_t)(n + 1) * 4);
  float* dinv    = (float*)take((size_t)n * 4);
  uint*  tmp     = (uint*)take((size_t)E * 4);
  int*   col     = (int*)take((size_t)E * 4);
  ush*   xs      = (ush*)take((size_t)n * 64 * 2);
  ush*   axs     = (ush*)take((size_t)n * 64 * 2);
  ush*   y1      = (ush*)take((size_t)n * 128 * 2);
  ush*   h2s     = xs;  // xs dead after aggx; reuse

  hipMemsetAsync(bcnt, 0, NBUCK_MAX * 4, stream);

  int pb = (E + CHUNK - 1) / CHUNK;  // 196
  bucket_count<<<pb, 256, 0, stream>>>(edst, bcnt, E);
  bucket_scan<<<1, 256, 0, stream>>>(bcnt, bbase, bnext, E);
  partition_kernel<<<pb, 256, 0, stream>>>(esrc, edst, bnext, tmp, E);
  csr_finalize<<<NBUCK, 256, 0, stream>>>(tmp, bbase, x, row_ptr, dinv, col, xs, n, E);

  aggx_kernel<<<(n + 3) / 4, 256, 0, stream>>>(xs, dinv, row_ptr, col, axs, n);
  gemm1_mfma<<<512, 256, 0, stream>>>(axs, W1, b1, y1, n);
  gemm2_mfma<<<512, 256, 0, stream>>>(y1, W2, dinv, h2s, n);
  agg2_kernel<<<(n + 3) / 4, 256, 0, stream>>>(h2s, dinv, row_ptr, col, b2, x,
                                               (float*)d_out, n);
}